// Round 4
// baseline (92.960 us; speedup 1.0000x reference)
//
#include <hip/hip_runtime.h>
#include <hip/hip_bf16.h>

// Shapes
#define B_ 64
#define L_ 64
#define D_ 512
#define F_ 32
#define H_ 512
#define M_ROWS 2048   // B*F_ neighbor rows
#define M2 2112       // + 64 [f0|m0] rows
#define KA 1024       // packed K ([self|aggr])

typedef __attribute__((ext_vector_type(8))) short bf16x8;
typedef __attribute__((ext_vector_type(4))) float f32x4;

__device__ __forceinline__ float leaky(float v) { return v > 0.0f ? v : 0.01f * v; }

__device__ __forceinline__ unsigned short f2bf(float v) {
  unsigned int b = __float_as_uint(v);
  unsigned int r = b + 0x7FFF + ((b >> 16) & 1);  // round-to-nearest-even
  return (unsigned short)(r >> 16);
}
__device__ __forceinline__ float bf2f(unsigned short h) {
  return __uint_as_float(((unsigned int)h) << 16);
}
__device__ __forceinline__ void cvt_store4(unsigned short* ph, unsigned short* pl, float4 v) {
  ushort4 h, l;
  h.x = f2bf(v.x); l.x = f2bf(v.x - bf2f(h.x));
  h.y = f2bf(v.y); l.y = f2bf(v.y - bf2f(h.y));
  h.z = f2bf(v.z); l.z = f2bf(v.z - bf2f(h.z));
  h.w = f2bf(v.w); l.w = f2bf(v.w - bf2f(h.w));
  *(ushort4*)ph = h;
  *(ushort4*)pl = l;
}

// Kernel 1: transpose + hi/lo-split both weight cats.
// cat 0: W0cat[k][n] = Ws0[k][n] (k<512) | Wa0[k-512][n]  -> W0t_{hi,lo}[n][k]
// cat 1: same with Ws1/Wa1 -> W1t_{hi,lo}[n][k]
// grid (16 k-tiles, 8 n-tiles, 2 cats), 256 thr, 64x64 tiles.
__global__ __launch_bounds__(256) void split_w(
    const float* __restrict__ Ws0, const float* __restrict__ Wa0,
    const float* __restrict__ Ws1, const float* __restrict__ Wa1,
    unsigned short* __restrict__ W0thi, unsigned short* __restrict__ W0tlo,
    unsigned short* __restrict__ W1thi, unsigned short* __restrict__ W1tlo) {
  __shared__ float lds[64][69];
  const int t = threadIdx.x;
  const int k0 = blockIdx.x * 64;
  const int n0 = blockIdx.y * 64;
  const int cat = blockIdx.z;
  const float* src = (cat == 0)
      ? (k0 < 512 ? Ws0 + (size_t)k0 * H_ : Wa0 + (size_t)(k0 - 512) * H_)
      : (k0 < 512 ? Ws1 + (size_t)k0 * H_ : Wa1 + (size_t)(k0 - 512) * H_);
  unsigned short* dhi = (cat == 0) ? W0thi : W1thi;
  unsigned short* dlo = (cat == 0) ? W0tlo : W1tlo;
#pragma unroll
  for (int i = 0; i < 4; ++i) {
    const int idx4 = t + 256 * i;          // 0..1023 float4 ids
    const int kl = idx4 >> 4;              // 0..63
    const int n4 = (idx4 & 15) * 4;        // 0..60
    *(float4*)&lds[kl][n4] = *(const float4*)(src + (size_t)kl * H_ + n0 + n4);
  }
  __syncthreads();
#pragma unroll
  for (int i = 0; i < 4; ++i) {
    const int idx4 = t + 256 * i;
    const int nl = idx4 >> 4;              // 0..63
    const int k4 = (idx4 & 15) * 4;        // 0..60
    ushort4 h, l;
    float v0 = lds[k4 + 0][nl], v1 = lds[k4 + 1][nl];
    float v2 = lds[k4 + 2][nl], v3 = lds[k4 + 3][nl];
    h.x = f2bf(v0); l.x = f2bf(v0 - bf2f(h.x));
    h.y = f2bf(v1); l.y = f2bf(v1 - bf2f(h.y));
    h.z = f2bf(v2); l.z = f2bf(v2 - bf2f(h.z));
    h.w = f2bf(v3); l.w = f2bf(v3 - bf2f(h.w));
    *(ushort4*)(dhi + (size_t)(n0 + nl) * KA + k0 + k4) = h;
    *(ushort4*)(dlo + (size_t)(n0 + nl) * KA + k0 + k4) = l;
  }
}

// Kernel 2: build A (2112 x 1024) as bf16 hi/lo planes.
// rows 0..2047: [x[b,idx1[b,f],:] | mean_j x[b,idx2[b,f,j],:]]
// rows 2048..2111: [x[b,0,:] | mean_j x[b,idx1[b,j],:]]
__global__ __launch_bounds__(128) void gather_pack(
    const float* __restrict__ x, const int* __restrict__ idx1,
    const int* __restrict__ idx2, unsigned short* __restrict__ Ahi,
    unsigned short* __restrict__ Alo) {
  const int blk = blockIdx.x;
  const int t = threadIdx.x;  // float4 col group
  unsigned short* dhi = Ahi + (size_t)blk * KA;
  unsigned short* dlo = Alo + (size_t)blk * KA;
  const float* xb;
  const int* gl;
  int r1;
  if (blk < M_ROWS) {
    const int b = blk >> 5;
    xb = x + (size_t)b * (L_ * D_);
    r1 = idx1[blk];
    gl = idx2 + (size_t)blk * F_;
  } else {
    const int b = blk - M_ROWS;
    xb = x + (size_t)b * (L_ * D_);
    r1 = 0;
    gl = idx1 + b * F_;
  }
  const float4 v = *(const float4*)(xb + (size_t)r1 * D_ + t * 4);
  cvt_store4(dhi + t * 4, dlo + t * 4, v);
  float4 acc = make_float4(0.f, 0.f, 0.f, 0.f);
#pragma unroll 4
  for (int j = 0; j < 32; ++j) {
    const float4 w = *(const float4*)(xb + (size_t)gl[j] * D_ + t * 4);
    acc.x += w.x; acc.y += w.y; acc.z += w.z; acc.w += w.w;
  }
  const float s = 1.0f / 32.0f;
  acc.x *= s; acc.y *= s; acc.z *= s; acc.w *= s;
  cvt_store4(dhi + D_ + t * 4, dlo + D_ + t * 4, acc);
}

// Kernel 3: MFMA GEMM (M=2112, N=512, K=1024), 3-term bf16 hi/lo split,
// fused bias+leaky, fused mean-over-F. Writes hm=[h0|mh1] hi/lo (64x1024).
// Tile 64x64, grid (33, 8), 128 thr = 2 waves; wave w owns rows bm+w*32..+31.
__global__ __launch_bounds__(128) void gemm1(
    const unsigned short* __restrict__ Ahi, const unsigned short* __restrict__ Alo,
    const unsigned short* __restrict__ Wthi, const unsigned short* __restrict__ Wtlo,
    const float* __restrict__ b0, unsigned short* __restrict__ Hhi,
    unsigned short* __restrict__ Hlo) {
  const int lane = threadIdx.x & 63;
  const int w = threadIdx.x >> 6;
  const int bm = blockIdx.x * 64;
  const int bn = blockIdx.y * 64;
  const int lr = lane & 15;
  const int lkb = (lane >> 4) * 8;

  const unsigned short* a0h = Ahi + (size_t)(bm + w * 32 + lr) * KA + lkb;
  const unsigned short* a0l = Alo + (size_t)(bm + w * 32 + lr) * KA + lkb;
  const unsigned short* a1h = a0h + 16 * KA;
  const unsigned short* a1l = a0l + 16 * KA;
  const unsigned short* bh0 = Wthi + (size_t)(bn + lr) * KA + lkb;
  const unsigned short* bl0 = Wtlo + (size_t)(bn + lr) * KA + lkb;

  f32x4 acc[2][4] = {};

#pragma unroll 2
  for (int k0 = 0; k0 < 1024; k0 += 32) {
    const bf16x8 A0h = *(const bf16x8*)(a0h + k0);
    const bf16x8 A1h = *(const bf16x8*)(a1h + k0);
    const bf16x8 A0l = *(const bf16x8*)(a0l + k0);
    const bf16x8 A1l = *(const bf16x8*)(a1l + k0);
#pragma unroll
    for (int ni = 0; ni < 4; ++ni) {
      const bf16x8 Bh = *(const bf16x8*)(bh0 + ni * 16 * KA + k0);
      const bf16x8 Bl = *(const bf16x8*)(bl0 + ni * 16 * KA + k0);
      acc[0][ni] = __builtin_amdgcn_mfma_f32_16x16x32_bf16(A0h, Bh, acc[0][ni], 0, 0, 0);
      acc[0][ni] = __builtin_amdgcn_mfma_f32_16x16x32_bf16(A0h, Bl, acc[0][ni], 0, 0, 0);
      acc[0][ni] = __builtin_amdgcn_mfma_f32_16x16x32_bf16(A0l, Bh, acc[0][ni], 0, 0, 0);
      acc[1][ni] = __builtin_amdgcn_mfma_f32_16x16x32_bf16(A1h, Bh, acc[1][ni], 0, 0, 0);
      acc[1][ni] = __builtin_amdgcn_mfma_f32_16x16x32_bf16(A1h, Bl, acc[1][ni], 0, 0, 0);
      acc[1][ni] = __builtin_amdgcn_mfma_f32_16x16x32_bf16(A1l, Bh, acc[1][ni], 0, 0, 0);
    }
  }

  // C/D layout (verified m89/m91): col = lane&15, row = (lane>>4)*4 + reg
  if (blockIdx.x < 32) {
    // neighbor rows: rows of wave w are exactly b = 2*bx + w's 32 f-rows.
    const int b = blockIdx.x * 2 + w;
#pragma unroll
    for (int ni = 0; ni < 4; ++ni) {
      const int col = bn + ni * 16 + lr;
      const float bias = b0[col];
      float s = 0.f;
#pragma unroll
      for (int mi = 0; mi < 2; ++mi)
#pragma unroll
        for (int r = 0; r < 4; ++r) s += leaky(acc[mi][ni][r] + bias);
      s += __shfl_xor(s, 16);
      s += __shfl_xor(s, 32);
      s *= (1.0f / 32.0f);
      if (lane < 16) {
        const unsigned short h = f2bf(s);
        Hhi[(size_t)b * KA + 512 + col] = h;
        Hlo[(size_t)b * KA + 512 + col] = f2bf(s - bf2f(h));
      }
    }
  } else {
    // h0 rows (bm==2048): row index within block IS b.
#pragma unroll
    for (int ni = 0; ni < 4; ++ni) {
      const int col = bn + ni * 16 + lr;
      const float bias = b0[col];
#pragma unroll
      for (int mi = 0; mi < 2; ++mi)
#pragma unroll
        for (int r = 0; r < 4; ++r) {
          const int b = w * 32 + mi * 16 + (lane >> 4) * 4 + r;
          const float v = leaky(acc[mi][ni][r] + bias);
          const unsigned short h = f2bf(v);
          Hhi[(size_t)b * KA + col] = h;
          Hlo[(size_t)b * KA + col] = f2bf(v - bf2f(h));
        }
    }
  }
}

// Kernel 4: out = hm @ [Ws1;Wa1] + b1. M=64, N=512, K=1024.
// grid 32 (16-col tiles), 64 thr = 1 wave, wave does 4 m-frags x 1 n-frag.
__global__ __launch_bounds__(64) void gemm2(
    const unsigned short* __restrict__ Hhi, const unsigned short* __restrict__ Hlo,
    const unsigned short* __restrict__ Wthi, const unsigned short* __restrict__ Wtlo,
    const float* __restrict__ b1, float* __restrict__ out) {
  const int lane = threadIdx.x;
  const int n0 = blockIdx.x * 16;
  const int lr = lane & 15;
  const int lkb = (lane >> 4) * 8;
  const unsigned short* bh = Wthi + (size_t)(n0 + lr) * KA + lkb;
  const unsigned short* bl = Wtlo + (size_t)(n0 + lr) * KA + lkb;
  const unsigned short* ah = Hhi + (size_t)lr * KA + lkb;
  const unsigned short* al = Hlo + (size_t)lr * KA + lkb;
  f32x4 acc[4] = {};
#pragma unroll 2
  for (int k0 = 0; k0 < 1024; k0 += 32) {
    const bf16x8 Bh = *(const bf16x8*)(bh + k0);
    const bf16x8 Bl = *(const bf16x8*)(bl + k0);
#pragma unroll
    for (int mi = 0; mi < 4; ++mi) {
      const bf16x8 Ah = *(const bf16x8*)(ah + (size_t)mi * 16 * KA + k0);
      const bf16x8 Al = *(const bf16x8*)(al + (size_t)mi * 16 * KA + k0);
      acc[mi] = __builtin_amdgcn_mfma_f32_16x16x32_bf16(Ah, Bh, acc[mi], 0, 0, 0);
      acc[mi] = __builtin_amdgcn_mfma_f32_16x16x32_bf16(Ah, Bl, acc[mi], 0, 0, 0);
      acc[mi] = __builtin_amdgcn_mfma_f32_16x16x32_bf16(Al, Bh, acc[mi], 0, 0, 0);
    }
  }
  const int col = n0 + lr;
  const float bias = b1[col];
#pragma unroll
  for (int mi = 0; mi < 4; ++mi)
#pragma unroll
    for (int r = 0; r < 4; ++r) {
      const int row = mi * 16 + (lane >> 4) * 4 + r;
      out[(size_t)row * H_ + col] = acc[mi][r] + bias;
    }
}

extern "C" void kernel_launch(void* const* d_in, const int* in_sizes, int n_in,
                              void* d_out, int out_size, void* d_ws, size_t ws_size,
                              hipStream_t stream) {
  const float* x    = (const float*)d_in[0];
  const int*   idx1 = (const int*)d_in[1];
  const int*   idx2 = (const int*)d_in[2];
  const float* Wa0  = (const float*)d_in[3];
  const float* b0   = (const float*)d_in[4];
  const float* Ws0  = (const float*)d_in[5];
  const float* Wa1  = (const float*)d_in[6];
  const float* b1   = (const float*)d_in[7];
  const float* Ws1  = (const float*)d_in[8];
  float* out = (float*)d_out;

  unsigned short* wsu = (unsigned short*)d_ws;
  unsigned short* Ahi   = wsu;                         // 2112*1024
  unsigned short* Alo   = Ahi + (size_t)M2 * KA;       // 2112*1024
  unsigned short* W0thi = Alo + (size_t)M2 * KA;       // 512*1024
  unsigned short* W0tlo = W0thi + (size_t)H_ * KA;
  unsigned short* W1thi = W0tlo + (size_t)H_ * KA;
  unsigned short* W1tlo = W1thi + (size_t)H_ * KA;
  unsigned short* Hhi   = W1tlo + (size_t)H_ * KA;     // 64*1024
  unsigned short* Hlo   = Hhi + (size_t)B_ * KA;       // 64*1024

  split_w<<<dim3(16, 8, 2), 256, 0, stream>>>(Ws0, Wa0, Ws1, Wa1,
                                              W0thi, W0tlo, W1thi, W1tlo);
  gather_pack<<<M2, 128, 0, stream>>>(x, idx1, idx2, Ahi, Alo);
  gemm1<<<dim3(33, 8), 128, 0, stream>>>(Ahi, Alo, W0thi, W0tlo, b0, Hhi, Hlo);
  gemm2<<<32, 64, 0, stream>>>(Hhi, Hlo, W1thi, W1tlo, b1, out);
}

// Round 5
// 52.321 us; speedup vs baseline: 1.7767x; 1.7767x over previous
//
#include <hip/hip_runtime.h>
#include <hip/hip_bf16.h>

// Shapes
#define B_ 64
#define L_ 64
#define D_ 512
#define F_ 32
#define H_ 512
#define M_ROWS 2048   // B*F_ neighbor rows
#define M2 2112       // + 64 [f0|m0] rows  (= 33 * 64, no tail)
#define KA 1024       // packed K ([self|aggr])

typedef __attribute__((ext_vector_type(8))) short bf16x8;
typedef __attribute__((ext_vector_type(4))) float f32x4;

__device__ __forceinline__ float leaky(float v) { return v > 0.0f ? v : 0.01f * v; }

__device__ __forceinline__ unsigned short f2bf(float v) {
  unsigned int b = __float_as_uint(v);
  unsigned int r = b + 0x7FFF + ((b >> 16) & 1);  // RNE
  return (unsigned short)(r >> 16);
}
__device__ __forceinline__ float bf2f(unsigned short h) {
  return __uint_as_float(((unsigned int)h) << 16);
}
__device__ __forceinline__ void cvt_store4(unsigned short* ph, unsigned short* pl, float4 v) {
  ushort4 h, l;
  h.x = f2bf(v.x); l.x = f2bf(v.x - bf2f(h.x));
  h.y = f2bf(v.y); l.y = f2bf(v.y - bf2f(h.y));
  h.z = f2bf(v.z); l.z = f2bf(v.z - bf2f(h.z));
  h.w = f2bf(v.w); l.w = f2bf(v.w - bf2f(h.w));
  *(ushort4*)ph = h;
  *(ushort4*)pl = l;
}

#define GLOAD16(GP, LP)                                              \
  __builtin_amdgcn_global_load_lds(                                  \
      (const __attribute__((address_space(1))) unsigned int*)(GP),   \
      (__attribute__((address_space(3))) unsigned int*)(LP), 16, 0, 0)

// ---------------- Kernel 1: weight transpose + hi/lo split ----------------
__global__ __launch_bounds__(256) void split_w(
    const float* __restrict__ Ws0, const float* __restrict__ Wa0,
    const float* __restrict__ Ws1, const float* __restrict__ Wa1,
    unsigned short* __restrict__ W0thi, unsigned short* __restrict__ W0tlo,
    unsigned short* __restrict__ W1thi, unsigned short* __restrict__ W1tlo) {
  __shared__ float lt[64][69];
  const int t = threadIdx.x;
  const int k0 = blockIdx.x * 64;
  const int n0 = blockIdx.y * 64;
  const int cat = blockIdx.z;
  const float* src = (cat == 0)
      ? (k0 < 512 ? Ws0 + (size_t)k0 * H_ : Wa0 + (size_t)(k0 - 512) * H_)
      : (k0 < 512 ? Ws1 + (size_t)k0 * H_ : Wa1 + (size_t)(k0 - 512) * H_);
  unsigned short* dhi = (cat == 0) ? W0thi : W1thi;
  unsigned short* dlo = (cat == 0) ? W0tlo : W1tlo;
#pragma unroll
  for (int i = 0; i < 4; ++i) {
    const int idx4 = t + 256 * i;
    const int kl = idx4 >> 4;
    const int n4 = (idx4 & 15) * 4;
    *(float4*)&lt[kl][n4] = *(const float4*)(src + (size_t)kl * H_ + n0 + n4);
  }
  __syncthreads();
#pragma unroll
  for (int i = 0; i < 4; ++i) {
    const int idx4 = t + 256 * i;
    const int nl = idx4 >> 4;
    const int k4 = (idx4 & 15) * 4;
    ushort4 h, l;
    float v0 = lt[k4 + 0][nl], v1 = lt[k4 + 1][nl];
    float v2 = lt[k4 + 2][nl], v3 = lt[k4 + 3][nl];
    h.x = f2bf(v0); l.x = f2bf(v0 - bf2f(h.x));
    h.y = f2bf(v1); l.y = f2bf(v1 - bf2f(h.y));
    h.z = f2bf(v2); l.z = f2bf(v2 - bf2f(h.z));
    h.w = f2bf(v3); l.w = f2bf(v3 - bf2f(h.w));
    *(ushort4*)(dhi + (size_t)(n0 + nl) * KA + k0 + k4) = h;
    *(ushort4*)(dlo + (size_t)(n0 + nl) * KA + k0 + k4) = l;
  }
}

// ---------------- Kernel 2: gather + mean + hi/lo split of A ----------------
__global__ __launch_bounds__(128) void gather_pack(
    const float* __restrict__ x, const int* __restrict__ idx1,
    const int* __restrict__ idx2, unsigned short* __restrict__ Ahi,
    unsigned short* __restrict__ Alo) {
  const int blk = blockIdx.x;
  const int t = threadIdx.x;
  unsigned short* dhi = Ahi + (size_t)blk * KA;
  unsigned short* dlo = Alo + (size_t)blk * KA;
  const float* xb;
  const int* gl;
  int r1;
  if (blk < M_ROWS) {
    const int b = blk >> 5;
    xb = x + (size_t)b * (L_ * D_);
    r1 = idx1[blk];
    gl = idx2 + (size_t)blk * F_;
  } else {
    const int b = blk - M_ROWS;
    xb = x + (size_t)b * (L_ * D_);
    r1 = 0;
    gl = idx1 + b * F_;
  }
  const float4 v = *(const float4*)(xb + (size_t)r1 * D_ + t * 4);
  cvt_store4(dhi + t * 4, dlo + t * 4, v);
  float4 acc = make_float4(0.f, 0.f, 0.f, 0.f);
#pragma unroll 4
  for (int j = 0; j < 32; ++j) {
    const float4 w = *(const float4*)(xb + (size_t)gl[j] * D_ + t * 4);
    acc.x += w.x; acc.y += w.y; acc.z += w.z; acc.w += w.w;
  }
  const float s = 1.0f / 32.0f;
  acc.x *= s; acc.y *= s; acc.z *= s; acc.w *= s;
  cvt_store4(dhi + D_ + t * 4, dlo + D_ + t * 4, acc);
}

// ---------------- Kernel 3: LDS-staged dbuf MFMA GEMM + fused epilogue ------
// C = A(2112x1024) @ Wt(512x1024)^T, 3-term bf16 hi/lo. BM=BN=64, BK=64,
// 4 waves (2x2), double-buffered LDS, global_load_lds w/ XOR-preswizzled src.
// Epilogue: bias+leaky; neighbor blocks also mean-over-32-rows -> hm[b][512+c].
__global__ __launch_bounds__(256) void gemm1(
    const unsigned short* __restrict__ Ahi, const unsigned short* __restrict__ Alo,
    const unsigned short* __restrict__ Wthi, const unsigned short* __restrict__ Wtlo,
    const float* __restrict__ b0, unsigned short* __restrict__ Hhi,
    unsigned short* __restrict__ Hlo) {
  // LDS: 2 bufs x 4 planes (Ah,Al,Bh,Bl) x [64 rows][64 k] bf16
  __shared__ unsigned short lds[32768];  // 64 KB
  const int tid = threadIdx.x;
  const int lane = tid & 63;
  const int w = tid >> 6;         // wave 0..3: stages plane w
  const int wr = w >> 1, wc = w & 1;
  const int lr = lane & 15;
  const int kb = lane >> 4;       // 0..3
  const int swz = lr & 7;
  const int bm = blockIdx.x * 64;
  const int bn = blockIdx.y * 64;

  // staging source base for this wave's plane
  const unsigned short* P = (w == 0) ? Ahi : (w == 1) ? Alo : (w == 2) ? Wthi : Wtlo;
  const int row0 = (w < 2) ? bm : bn;
  const unsigned short* gbase =
      P + (size_t)(row0 + (lane >> 3)) * KA + ((lane & 7) ^ ((lane >> 3) & 7)) * 8;

  f32x4 acc[2][2] = {};

  // prologue: stage buffer 0 (k-tile 0)
#pragma unroll
  for (int i = 0; i < 8; ++i)
    GLOAD16(gbase + (size_t)i * 8 * KA, &lds[w * 4096 + i * 512]);
  __syncthreads();

#define LDSFRAG(PL, ROW, CB) \
  (*(const bf16x8*)&lds[buf * 16384 + (PL)*4096 + (ROW)*64 + (((CB) ^ swz) * 8)])

  for (int kt = 0; kt < 16; ++kt) {
    const int buf = kt & 1;
    if (kt < 15) {
      const unsigned short* g2 = gbase + (kt + 1) * 64;
#pragma unroll
      for (int i = 0; i < 8; ++i)
        GLOAD16(g2 + (size_t)i * 8 * KA, &lds[(buf ^ 1) * 16384 + w * 4096 + i * 512]);
    }
#pragma unroll
    for (int ks = 0; ks < 2; ++ks) {
      const int c = ks * 4 + kb;
      const bf16x8 Ah0 = LDSFRAG(0, wr * 32 + lr, c);
      const bf16x8 Ah1 = LDSFRAG(0, wr * 32 + 16 + lr, c);
      const bf16x8 Al0 = LDSFRAG(1, wr * 32 + lr, c);
      const bf16x8 Al1 = LDSFRAG(1, wr * 32 + 16 + lr, c);
      const bf16x8 Bh0 = LDSFRAG(2, wc * 32 + lr, c);
      const bf16x8 Bh1 = LDSFRAG(2, wc * 32 + 16 + lr, c);
      const bf16x8 Bl0 = LDSFRAG(3, wc * 32 + lr, c);
      const bf16x8 Bl1 = LDSFRAG(3, wc * 32 + 16 + lr, c);
      acc[0][0] = __builtin_amdgcn_mfma_f32_16x16x32_bf16(Ah0, Bh0, acc[0][0], 0, 0, 0);
      acc[0][0] = __builtin_amdgcn_mfma_f32_16x16x32_bf16(Ah0, Bl0, acc[0][0], 0, 0, 0);
      acc[0][0] = __builtin_amdgcn_mfma_f32_16x16x32_bf16(Al0, Bh0, acc[0][0], 0, 0, 0);
      acc[0][1] = __builtin_amdgcn_mfma_f32_16x16x32_bf16(Ah0, Bh1, acc[0][1], 0, 0, 0);
      acc[0][1] = __builtin_amdgcn_mfma_f32_16x16x32_bf16(Ah0, Bl1, acc[0][1], 0, 0, 0);
      acc[0][1] = __builtin_amdgcn_mfma_f32_16x16x32_bf16(Al0, Bh1, acc[0][1], 0, 0, 0);
      acc[1][0] = __builtin_amdgcn_mfma_f32_16x16x32_bf16(Ah1, Bh0, acc[1][0], 0, 0, 0);
      acc[1][0] = __builtin_amdgcn_mfma_f32_16x16x32_bf16(Ah1, Bl0, acc[1][0], 0, 0, 0);
      acc[1][0] = __builtin_amdgcn_mfma_f32_16x16x32_bf16(Al1, Bh0, acc[1][0], 0, 0, 0);
      acc[1][1] = __builtin_amdgcn_mfma_f32_16x16x32_bf16(Ah1, Bh1, acc[1][1], 0, 0, 0);
      acc[1][1] = __builtin_amdgcn_mfma_f32_16x16x32_bf16(Ah1, Bl1, acc[1][1], 0, 0, 0);
      acc[1][1] = __builtin_amdgcn_mfma_f32_16x16x32_bf16(Al1, Bh1, acc[1][1], 0, 0, 0);
    }
    __syncthreads();  // drains staging vmcnt + protects buf reuse
  }
#undef LDSFRAG

  // Epilogue. C/D layout: col = lane&15, row = (lane>>4)*4 + reg (m89/m91).
  if (blockIdx.x < 32) {
    // neighbor rows: wave wr's 32 rows = all f of b = 2*bx + wr
    const int b = blockIdx.x * 2 + wr;
#pragma unroll
    for (int ni = 0; ni < 2; ++ni) {
      const int col = bn + wc * 32 + ni * 16 + lr;
      const float bias = b0[col];
      float s = 0.f;
#pragma unroll
      for (int mi = 0; mi < 2; ++mi)
#pragma unroll
        for (int r = 0; r < 4; ++r) s += leaky(acc[mi][ni][r] + bias);
      s += __shfl_xor(s, 16);
      s += __shfl_xor(s, 32);
      s *= (1.0f / 32.0f);
      if (lane < 16) {
        const unsigned short h = f2bf(s);
        Hhi[(size_t)b * KA + 512 + col] = h;
        Hlo[(size_t)b * KA + 512 + col] = f2bf(s - bf2f(h));
      }
    }
  } else {
    // h0 rows: bm == 2048, local row == b
#pragma unroll
    for (int ni = 0; ni < 2; ++ni) {
      const int col = bn + wc * 32 + ni * 16 + lr;
      const float bias = b0[col];
#pragma unroll
      for (int mi = 0; mi < 2; ++mi)
#pragma unroll
        for (int r = 0; r < 4; ++r) {
          const int b = wr * 32 + mi * 16 + kb * 4 + r;
          const float v = leaky(acc[mi][ni][r] + bias);
          const unsigned short h = f2bf(v);
          Hhi[(size_t)b * KA + col] = h;
          Hlo[(size_t)b * KA + col] = f2bf(v - bf2f(h));
        }
    }
  }
}

// ---------------- Kernel 4: out = hm @ W1t^T + b1 (M=64,N=512,K=1024) -------
// 4 waves split-K (256 each), LDS reduce. grid 32 (16-col tiles).
__global__ __launch_bounds__(256) void gemm2(
    const unsigned short* __restrict__ Hhi, const unsigned short* __restrict__ Hlo,
    const unsigned short* __restrict__ Wthi, const unsigned short* __restrict__ Wtlo,
    const float* __restrict__ b1, float* __restrict__ out) {
  __shared__ float sacc[256][17];
  const int tid = threadIdx.x;
  const int w = tid >> 6;
  const int lane = tid & 63;
  const int lr = lane & 15;
  const int kb = lane >> 4;
  const int n0 = blockIdx.x * 16;

  f32x4 acc[4] = {};
  const int kw = w * 256;
#pragma unroll 2
  for (int ks = 0; ks < 8; ++ks) {
    const int k = kw + ks * 32 + kb * 8;
    const bf16x8 Bh = *(const bf16x8*)(Wthi + (size_t)(n0 + lr) * KA + k);
    const bf16x8 Bl = *(const bf16x8*)(Wtlo + (size_t)(n0 + lr) * KA + k);
#pragma unroll
    for (int mi = 0; mi < 4; ++mi) {
      const bf16x8 Ah = *(const bf16x8*)(Hhi + (size_t)(mi * 16 + lr) * KA + k);
      const bf16x8 Al = *(const bf16x8*)(Hlo + (size_t)(mi * 16 + lr) * KA + k);
      acc[mi] = __builtin_amdgcn_mfma_f32_16x16x32_bf16(Ah, Bh, acc[mi], 0, 0, 0);
      acc[mi] = __builtin_amdgcn_mfma_f32_16x16x32_bf16(Ah, Bl, acc[mi], 0, 0, 0);
      acc[mi] = __builtin_amdgcn_mfma_f32_16x16x32_bf16(Al, Bh, acc[mi], 0, 0, 0);
    }
  }
#pragma unroll
  for (int mi = 0; mi < 4; ++mi)
#pragma unroll
    for (int r = 0; r < 4; ++r)
      sacc[((w * 4 + mi) * 4 + kb) * 4 + r][lr] = acc[mi][r];
  __syncthreads();

  // 1024 outputs, 4 per thread
  const int lr2 = tid & 15;
  const int rg = tid >> 4;  // 0..15
#pragma unroll
  for (int q = 0; q < 4; ++q) {
    const int row = rg * 4 + q;
    const int mi = row >> 4, kb2 = (row >> 2) & 3, r = row & 3;
    float s = b1[n0 + lr2];
#pragma unroll
    for (int w2 = 0; w2 < 4; ++w2)
      s += sacc[((w2 * 4 + mi) * 4 + kb2) * 4 + r][lr2];
    out[(size_t)row * H_ + n0 + lr2] = s;
  }
}

extern "C" void kernel_launch(void* const* d_in, const int* in_sizes, int n_in,
                              void* d_out, int out_size, void* d_ws, size_t ws_size,
                              hipStream_t stream) {
  const float* x    = (const float*)d_in[0];
  const int*   idx1 = (const int*)d_in[1];
  const int*   idx2 = (const int*)d_in[2];
  const float* Wa0  = (const float*)d_in[3];
  const float* b0   = (const float*)d_in[4];
  const float* Ws0  = (const float*)d_in[5];
  const float* Wa1  = (const float*)d_in[6];
  const float* b1   = (const float*)d_in[7];
  const float* Ws1  = (const float*)d_in[8];
  float* out = (float*)d_out;

  unsigned short* wsu = (unsigned short*)d_ws;
  unsigned short* Ahi   = wsu;                         // 2112*1024
  unsigned short* Alo   = Ahi + (size_t)M2 * KA;
  unsigned short* W0thi = Alo + (size_t)M2 * KA;       // 512*1024 each
  unsigned short* W0tlo = W0thi + (size_t)H_ * KA;
  unsigned short* W1thi = W0tlo + (size_t)H_ * KA;
  unsigned short* W1tlo = W1thi + (size_t)H_ * KA;
  unsigned short* Hhi   = W1tlo + (size_t)H_ * KA;     // 64*1024 each
  unsigned short* Hlo   = Hhi + (size_t)B_ * KA;

  split_w<<<dim3(16, 8, 2), 256, 0, stream>>>(Ws0, Wa0, Ws1, Wa1,
                                              W0thi, W0tlo, W1thi, W1tlo);
  gather_pack<<<M2, 128, 0, stream>>>(x, idx1, idx2, Ahi, Alo);
  gemm1<<<dim3(33, 8), 256, 0, stream>>>(Ahi, Alo, W0thi, W0tlo, b0, Hhi, Hlo);
  gemm2<<<32, 256, 0, stream>>>(Hhi, Hlo, W1thi, W1tlo, b1, out);
}

// Round 6
// 48.186 us; speedup vs baseline: 1.9292x; 1.0858x over previous
//
#include <hip/hip_runtime.h>
#include <hip/hip_bf16.h>

// Shapes
#define B_ 64
#define L_ 64
#define D_ 512
#define F_ 32
#define H_ 512
#define M_ROWS 2048   // B*F_ neighbor rows
#define M2 2112       // + 64 [f0|m0] rows  (= 33 * 64)
#define KA 1024       // GEMM1 K ([self|aggr])

typedef __attribute__((ext_vector_type(8))) short bf16x8;
typedef __attribute__((ext_vector_type(4))) float f32x4;

__device__ __forceinline__ float leaky(float v) { return v > 0.0f ? v : 0.01f * v; }

__device__ __forceinline__ unsigned short f2bf(float v) {
  unsigned int b = __float_as_uint(v);
  unsigned int r = b + 0x7FFF + ((b >> 16) & 1);  // RNE
  return (unsigned short)(r >> 16);
}
__device__ __forceinline__ float bf2f(unsigned short h) {
  return __uint_as_float(((unsigned int)h) << 16);
}
__device__ __forceinline__ void cvt_store4(unsigned short* ph, unsigned short* pl, float4 v) {
  ushort4 h, l;
  h.x = f2bf(v.x); l.x = f2bf(v.x - bf2f(h.x));
  h.y = f2bf(v.y); l.y = f2bf(v.y - bf2f(h.y));
  h.z = f2bf(v.z); l.z = f2bf(v.z - bf2f(h.z));
  h.w = f2bf(v.w); l.w = f2bf(v.w - bf2f(h.w));
  *(ushort4*)ph = h;
  *(ushort4*)pl = l;
}

#define GLOAD16(GP, LP)                                              \
  __builtin_amdgcn_global_load_lds(                                  \
      (const __attribute__((address_space(1))) unsigned int*)(GP),   \
      (__attribute__((address_space(3))) unsigned int*)(LP), 16, 0, 0)

// ---------------- Kernel 1: fused prep ----------------
// blocks [0,64):    x-split  -> Xhi/Xlo planes [4096][512] bf16
// blocks [64,320):  w-split  -> W0t/W1t hi/lo  [512][1024] bf16 (transposed cat)
// blocks [320,576): means    -> Mh/Ml [2112][512]: rows b*32+f = m1, 2048+b = m0
//                   via histogram count-matrix MFMA: m = (C/32) @ x_b
__global__ __launch_bounds__(256) void prep(
    const float* __restrict__ x, const int* __restrict__ idx1,
    const int* __restrict__ idx2,
    const float* __restrict__ Ws0, const float* __restrict__ Wa0,
    const float* __restrict__ Ws1, const float* __restrict__ Wa1,
    unsigned short* __restrict__ Xhi, unsigned short* __restrict__ Xlo,
    unsigned short* __restrict__ Mh, unsigned short* __restrict__ Ml,
    unsigned short* __restrict__ W0thi, unsigned short* __restrict__ W0tlo,
    unsigned short* __restrict__ W1thi, unsigned short* __restrict__ W1tlo) {
  __shared__ __align__(16) char smem[33024];
  const int blk = blockIdx.x;
  const int t = threadIdx.x;

  if (blk < 64) {
    // ---- x-split: b = blk, 64*512 floats -> bf16 hi/lo
    const int b = blk;
    const float* src = x + (size_t)b * (L_ * D_);
    unsigned short* dh = Xhi + (size_t)b * (L_ * D_);
    unsigned short* dl = Xlo + (size_t)b * (L_ * D_);
#pragma unroll 4
    for (int i = 0; i < 32; ++i) {
      const int f4 = t + 256 * i;  // 0..8191
      const float4 v = *(const float4*)(src + (size_t)f4 * 4);
      cvt_store4(dh + (size_t)f4 * 4, dl + (size_t)f4 * 4, v);
    }
  } else if (blk < 320) {
    // ---- w-split: q -> (k-tile 16, n-tile 8, cat 2)
    const int q = blk - 64;
    const int k0 = (q & 15) * 64;
    const int n0 = ((q >> 4) & 7) * 64;
    const int cat = q >> 7;
    float (*lt)[72] = (float(*)[72])smem;  // [64][72], 16B-aligned rows
    const float* src = (cat == 0)
        ? (k0 < 512 ? Ws0 + (size_t)k0 * H_ : Wa0 + (size_t)(k0 - 512) * H_)
        : (k0 < 512 ? Ws1 + (size_t)k0 * H_ : Wa1 + (size_t)(k0 - 512) * H_);
    unsigned short* dhi = (cat == 0) ? W0thi : W1thi;
    unsigned short* dlo = (cat == 0) ? W0tlo : W1tlo;
#pragma unroll
    for (int i = 0; i < 4; ++i) {
      const int idx4 = t + 256 * i;
      const int kl = idx4 >> 4;
      const int n4 = (idx4 & 15) * 4;
      *(float4*)&lt[kl][n4] = *(const float4*)(src + (size_t)kl * H_ + n0 + n4);
    }
    __syncthreads();
#pragma unroll
    for (int i = 0; i < 4; ++i) {
      const int idx4 = t + 256 * i;
      const int nl = idx4 >> 4;
      const int k4 = (idx4 & 15) * 4;
      ushort4 h, l;
      const float v0 = lt[k4 + 0][nl], v1 = lt[k4 + 1][nl];
      const float v2 = lt[k4 + 2][nl], v3 = lt[k4 + 3][nl];
      h.x = f2bf(v0); l.x = f2bf(v0 - bf2f(h.x));
      h.y = f2bf(v1); l.y = f2bf(v1 - bf2f(h.y));
      h.z = f2bf(v2); l.z = f2bf(v2 - bf2f(h.z));
      h.w = f2bf(v3); l.w = f2bf(v3 - bf2f(h.w));
      *(ushort4*)(dhi + (size_t)(n0 + nl) * KA + k0 + k4) = h;
      *(ushort4*)(dlo + (size_t)(n0 + nl) * KA + k0 + k4) = l;
    }
  } else {
    // ---- means: q = blk-320: b = q>>2, two 64-col tiles nt = (q&3)*2 + {0,1}
    const int q = blk - 320;
    const int b = q >> 2;
    const int nt0 = (q & 3) * 2;
    unsigned int* cnt = (unsigned int*)smem;              // [33][64]
    unsigned short* Cm = (unsigned short*)(smem + 8448);  // [48][64] bf16
    unsigned short* XTh = (unsigned short*)(smem + 14592);  // [64][72]
    unsigned short* XTl = XTh + 64 * 72;
    const int lane = t & 63;
    const int w = t >> 6;
    const int lr = lane & 15;
    const int kb8 = (lane >> 4) * 8;

#pragma unroll
    for (int i = 0; i < 9; ++i) { const int p = t + 256 * i; if (p < 2112) cnt[p] = 0u; }
#pragma unroll
    for (int i = 0; i < 12; ++i) Cm[t + 256 * i] = 0;
    __syncthreads();
#pragma unroll
    for (int i = 0; i < 4; ++i) {
      const int j = t + 256 * i;  // 0..1023; f = j>>5
      atomicAdd(&cnt[(j >> 5) * 64 + idx2[(size_t)b * 1024 + j]], 1u);
    }
    if (t < 32) atomicAdd(&cnt[32 * 64 + idx1[b * F_ + t]], 1u);
    __syncthreads();
    // counts/32 exact in bf16 (<=6 significant bits, pow2 scale)
#pragma unroll
    for (int i = 0; i < 9; ++i) {
      const int p = t + 256 * i;
      if (p < 2112) Cm[p] = f2bf((float)cnt[p] * 0.03125f);
    }
    __syncthreads();
    bf16x8 Af[3][2];
#pragma unroll
    for (int mi = 0; mi < 3; ++mi)
#pragma unroll
      for (int kt = 0; kt < 2; ++kt)
        Af[mi][kt] = *(const bf16x8*)&Cm[(mi * 16 + lr) * 64 + kt * 32 + kb8];

#pragma unroll
    for (int tt = 0; tt < 2; ++tt) {
      const int nbase = (nt0 + tt) * 64;
      // stage x_b[:, nbase:+64] transposed+split: XT[c][l]
#pragma unroll
      for (int i = 0; i < 4; ++i) {
        const int f4 = t + 256 * i;       // 0..1023
        const int l = f4 >> 4;
        const int c4 = (f4 & 15) * 4;
        const float4 v = *(const float4*)(x + (size_t)b * (L_ * D_) + (size_t)l * D_ + nbase + c4);
        unsigned short h;
        h = f2bf(v.x); XTh[(c4 + 0) * 72 + l] = h; XTl[(c4 + 0) * 72 + l] = f2bf(v.x - bf2f(h));
        h = f2bf(v.y); XTh[(c4 + 1) * 72 + l] = h; XTl[(c4 + 1) * 72 + l] = f2bf(v.y - bf2f(h));
        h = f2bf(v.z); XTh[(c4 + 2) * 72 + l] = h; XTl[(c4 + 2) * 72 + l] = f2bf(v.z - bf2f(h));
        h = f2bf(v.w); XTh[(c4 + 3) * 72 + l] = h; XTl[(c4 + 3) * 72 + l] = f2bf(v.w - bf2f(h));
      }
      __syncthreads();
      // wave w computes cols nbase + w*16 + lr
      f32x4 acc[3] = {};
#pragma unroll
      for (int kt = 0; kt < 2; ++kt) {
        const bf16x8 Bh = *(const bf16x8*)&XTh[(w * 16 + lr) * 72 + kt * 32 + kb8];
        const bf16x8 Bl = *(const bf16x8*)&XTl[(w * 16 + lr) * 72 + kt * 32 + kb8];
#pragma unroll
        for (int mi = 0; mi < 3; ++mi) {
          acc[mi] = __builtin_amdgcn_mfma_f32_16x16x32_bf16(Af[mi][kt], Bh, acc[mi], 0, 0, 0);
          acc[mi] = __builtin_amdgcn_mfma_f32_16x16x32_bf16(Af[mi][kt], Bl, acc[mi], 0, 0, 0);
        }
      }
      const int col = nbase + w * 16 + lr;
#pragma unroll
      for (int mi = 0; mi < 3; ++mi)
#pragma unroll
        for (int r = 0; r < 4; ++r) {
          const int row48 = mi * 16 + (lane >> 4) * 4 + r;
          if (row48 > 32) continue;  // pad rows
          const size_t Mrow = (row48 < 32) ? (size_t)(b * F_ + row48) : (size_t)(M_ROWS + b);
          const float v = acc[mi][r];
          const unsigned short h = f2bf(v);
          Mh[Mrow * 512 + col] = h;
          Ml[Mrow * 512 + col] = f2bf(v - bf2f(h));
        }
      __syncthreads();
    }
  }
}

// ---------------- Kernel 2: MFMA GEMM w/ indirect-gather staging ------------
// C = [f1|m] @ W0t^T, 3-term bf16 hi/lo. BM=BN=64, BK=64, 4 waves, dbuf LDS.
// kt 0..7: A-planes gathered from Xhi/Xlo rows (per-lane global addr);
// kt 8..15: from Mh/Ml rows bm.. direct. Fused bias+leaky+mean epilogue.
__global__ __launch_bounds__(256) void gemm1(
    const unsigned short* __restrict__ Xhi, const unsigned short* __restrict__ Xlo,
    const unsigned short* __restrict__ Mh, const unsigned short* __restrict__ Ml,
    const unsigned short* __restrict__ Wthi, const unsigned short* __restrict__ Wtlo,
    const int* __restrict__ idx1, const float* __restrict__ b0,
    unsigned short* __restrict__ Hhi, unsigned short* __restrict__ Hlo) {
  __shared__ unsigned short lds[32768];  // 2 bufs x 4 planes x [64][64]
  const int tid = threadIdx.x;
  const int lane = tid & 63;
  const int w = tid >> 6;  // wave w stages plane w
  const int wr = w >> 1, wc = w & 1;
  const int lr = lane & 15;
  const int kb = lane >> 4;
  const int swz = lr & 7;
  const int bm = blockIdx.x * 64;
  const int bn = blockIdx.y * 64;
  const int rsel = lane >> 3;                   // 0..7
  const int cbs = ((lane & 7) ^ rsel) * 8;      // swizzled col-block offset

  // per-lane gather rows for the X-half (waves 0/1)
  int xrow[8];
  if (w < 2) {
#pragma unroll
    for (int i = 0; i < 8; ++i) {
      const int R = bm + rsel + 8 * i;
      if (bm < M_ROWS) xrow[i] = (R >> 5) * 64 + idx1[R];
      else             xrow[i] = (R - M_ROWS) * 64;  // f0 row
    }
  }
  const unsigned short* Xp = (w == 0) ? Xhi : Xlo;
  const unsigned short* Mp = (w == 0) ? Mh : Ml;
  const unsigned short* Wp = (w == 2) ? Wthi : Wtlo;
  const unsigned short* mbase = Mp + (size_t)(bm + rsel) * 512 + cbs;
  const unsigned short* wbase = Wp + (size_t)(bn + rsel) * KA + cbs;

#define STAGE(KT, BUF)                                                        \
  {                                                                           \
    unsigned short* ldst = &lds[(BUF)*16384 + w * 4096];                      \
    if (w < 2) {                                                              \
      if ((KT) < 8) {                                                         \
        const int co = (KT)*64 + cbs;                                         \
        _Pragma("unroll") for (int i = 0; i < 8; ++i)                         \
            GLOAD16(Xp + (size_t)xrow[i] * 512 + co, ldst + i * 512);         \
      } else {                                                                \
        const unsigned short* mb = mbase + ((KT)-8) * 64;                     \
        _Pragma("unroll") for (int i = 0; i < 8; ++i)                         \
            GLOAD16(mb + (size_t)i * 8 * 512, ldst + i * 512);                \
      }                                                                       \
    } else {                                                                  \
      const unsigned short* wb = wbase + (KT)*64;                             \
      _Pragma("unroll") for (int i = 0; i < 8; ++i)                           \
          GLOAD16(wb + (size_t)i * 8 * KA, ldst + i * 512);                   \
    }                                                                         \
  }

  f32x4 acc[2][2] = {};
  STAGE(0, 0);
  __syncthreads();

#define LDSFRAG(PL, ROW, CB) \
  (*(const bf16x8*)&lds[buf * 16384 + (PL)*4096 + (ROW)*64 + (((CB) ^ swz) * 8)])

  for (int kt = 0; kt < 16; ++kt) {
    const int buf = kt & 1;
    if (kt < 15) STAGE(kt + 1, buf ^ 1);
#pragma unroll
    for (int ks = 0; ks < 2; ++ks) {
      const int c = ks * 4 + kb;
      const bf16x8 Ah0 = LDSFRAG(0, wr * 32 + lr, c);
      const bf16x8 Ah1 = LDSFRAG(0, wr * 32 + 16 + lr, c);
      const bf16x8 Al0 = LDSFRAG(1, wr * 32 + lr, c);
      const bf16x8 Al1 = LDSFRAG(1, wr * 32 + 16 + lr, c);
      const bf16x8 Bh0 = LDSFRAG(2, wc * 32 + lr, c);
      const bf16x8 Bh1 = LDSFRAG(2, wc * 32 + 16 + lr, c);
      const bf16x8 Bl0 = LDSFRAG(3, wc * 32 + lr, c);
      const bf16x8 Bl1 = LDSFRAG(3, wc * 32 + 16 + lr, c);
      acc[0][0] = __builtin_amdgcn_mfma_f32_16x16x32_bf16(Ah0, Bh0, acc[0][0], 0, 0, 0);
      acc[0][0] = __builtin_amdgcn_mfma_f32_16x16x32_bf16(Ah0, Bl0, acc[0][0], 0, 0, 0);
      acc[0][0] = __builtin_amdgcn_mfma_f32_16x16x32_bf16(Al0, Bh0, acc[0][0], 0, 0, 0);
      acc[0][1] = __builtin_amdgcn_mfma_f32_16x16x32_bf16(Ah0, Bh1, acc[0][1], 0, 0, 0);
      acc[0][1] = __builtin_amdgcn_mfma_f32_16x16x32_bf16(Ah0, Bl1, acc[0][1], 0, 0, 0);
      acc[0][1] = __builtin_amdgcn_mfma_f32_16x16x32_bf16(Al0, Bh1, acc[0][1], 0, 0, 0);
      acc[1][0] = __builtin_amdgcn_mfma_f32_16x16x32_bf16(Ah1, Bh0, acc[1][0], 0, 0, 0);
      acc[1][0] = __builtin_amdgcn_mfma_f32_16x16x32_bf16(Ah1, Bl0, acc[1][0], 0, 0, 0);
      acc[1][0] = __builtin_amdgcn_mfma_f32_16x16x32_bf16(Al1, Bh0, acc[1][0], 0, 0, 0);
      acc[1][1] = __builtin_amdgcn_mfma_f32_16x16x32_bf16(Ah1, Bh1, acc[1][1], 0, 0, 0);
      acc[1][1] = __builtin_amdgcn_mfma_f32_16x16x32_bf16(Ah1, Bl1, acc[1][1], 0, 0, 0);
      acc[1][1] = __builtin_amdgcn_mfma_f32_16x16x32_bf16(Al1, Bh1, acc[1][1], 0, 0, 0);
    }
    __syncthreads();
  }
#undef LDSFRAG
#undef STAGE

  // Epilogue. C/D layout: col = lane&15, row = (lane>>4)*4 + reg.
  if (blockIdx.x < 32) {
    const int b = blockIdx.x * 2 + wr;  // wave wr's 32 rows = all f of this b
#pragma unroll
    for (int ni = 0; ni < 2; ++ni) {
      const int col = bn + wc * 32 + ni * 16 + lr;
      const float bias = b0[col];
      float s = 0.f;
#pragma unroll
      for (int mi = 0; mi < 2; ++mi)
#pragma unroll
        for (int r = 0; r < 4; ++r) s += leaky(acc[mi][ni][r] + bias);
      s += __shfl_xor(s, 16);
      s += __shfl_xor(s, 32);
      s *= (1.0f / 32.0f);
      if (lane < 16) {
        const unsigned short h = f2bf(s);
        Hhi[(size_t)b * KA + 512 + col] = h;
        Hlo[(size_t)b * KA + 512 + col] = f2bf(s - bf2f(h));
      }
    }
  } else {
#pragma unroll
    for (int ni = 0; ni < 2; ++ni) {
      const int col = bn + wc * 32 + ni * 16 + lr;
      const float bias = b0[col];
#pragma unroll
      for (int mi = 0; mi < 2; ++mi)
#pragma unroll
        for (int r = 0; r < 4; ++r) {
          const int b = wr * 32 + mi * 16 + kb * 4 + r;
          const float v = leaky(acc[mi][ni][r] + bias);
          const unsigned short h = f2bf(v);
          Hhi[(size_t)b * KA + col] = h;
          Hlo[(size_t)b * KA + col] = f2bf(v - bf2f(h));
        }
    }
  }
}

// ---------------- Kernel 3: out = hm @ W1t^T + b1 (64x512, K=1024) ----------
__global__ __launch_bounds__(256) void gemm2(
    const unsigned short* __restrict__ Hhi, const unsigned short* __restrict__ Hlo,
    const unsigned short* __restrict__ Wthi, const unsigned short* __restrict__ Wtlo,
    const float* __restrict__ b1, float* __restrict__ out) {
  __shared__ float sacc[256][17];
  const int tid = threadIdx.x;
  const int w = tid >> 6;
  const int lane = tid & 63;
  const int lr = lane & 15;
  const int kb = lane >> 4;
  const int n0 = blockIdx.x * 16;

  f32x4 acc[4] = {};
  const int kw = w * 256;
#pragma unroll 2
  for (int ks = 0; ks < 8; ++ks) {
    const int k = kw + ks * 32 + kb * 8;
    const bf16x8 Bh = *(const bf16x8*)(Wthi + (size_t)(n0 + lr) * KA + k);
    const bf16x8 Bl = *(const bf16x8*)(Wtlo + (size_t)(n0 + lr) * KA + k);
#pragma unroll
    for (int mi = 0; mi < 4; ++mi) {
      const bf16x8 Ah = *(const bf16x8*)(Hhi + (size_t)(mi * 16 + lr) * KA + k);
      const bf16x8 Al = *(const bf16x8*)(Hlo + (size_t)(mi * 16 + lr) * KA + k);
      acc[mi] = __builtin_amdgcn_mfma_f32_16x16x32_bf16(Ah, Bh, acc[mi], 0, 0, 0);
      acc[mi] = __builtin_amdgcn_mfma_f32_16x16x32_bf16(Ah, Bl, acc[mi], 0, 0, 0);
      acc[mi] = __builtin_amdgcn_mfma_f32_16x16x32_bf16(Al, Bh, acc[mi], 0, 0, 0);
    }
  }
#pragma unroll
  for (int mi = 0; mi < 4; ++mi)
#pragma unroll
    for (int r = 0; r < 4; ++r)
      sacc[((w * 4 + mi) * 4 + kb) * 4 + r][lr] = acc[mi][r];
  __syncthreads();

  const int lr2 = tid & 15;
  const int rg = tid >> 4;
#pragma unroll
  for (int q = 0; q < 4; ++q) {
    const int row = rg * 4 + q;
    const int mi = row >> 4, kb2 = (row >> 2) & 3, r = row & 3;
    float s = b1[n0 + lr2];
#pragma unroll
    for (int w2 = 0; w2 < 4; ++w2)
      s += sacc[((w2 * 4 + mi) * 4 + kb2) * 4 + r][lr2];
    out[(size_t)row * H_ + n0 + lr2] = s;
  }
}

extern "C" void kernel_launch(void* const* d_in, const int* in_sizes, int n_in,
                              void* d_out, int out_size, void* d_ws, size_t ws_size,
                              hipStream_t stream) {
  const float* x    = (const float*)d_in[0];
  const int*   idx1 = (const int*)d_in[1];
  const int*   idx2 = (const int*)d_in[2];
  const float* Wa0  = (const float*)d_in[3];
  const float* b0   = (const float*)d_in[4];
  const float* Ws0  = (const float*)d_in[5];
  const float* Wa1  = (const float*)d_in[6];
  const float* b1   = (const float*)d_in[7];
  const float* Ws1  = (const float*)d_in[8];
  float* out = (float*)d_out;

  unsigned short* wsu = (unsigned short*)d_ws;
  unsigned short* Xhi   = wsu;                          // 4096*512
  unsigned short* Xlo   = Xhi + (size_t)4096 * 512;
  unsigned short* Mh    = Xlo + (size_t)4096 * 512;     // 2112*512
  unsigned short* Ml    = Mh + (size_t)M2 * 512;
  unsigned short* W0thi = Ml + (size_t)M2 * 512;        // 512*1024 each
  unsigned short* W0tlo = W0thi + (size_t)H_ * KA;
  unsigned short* W1thi = W0tlo + (size_t)H_ * KA;
  unsigned short* W1tlo = W1thi + (size_t)H_ * KA;
  unsigned short* Hhi   = W1tlo + (size_t)H_ * KA;      // 64*1024 each
  unsigned short* Hlo   = Hhi + (size_t)B_ * KA;

  prep<<<576, 256, 0, stream>>>(x, idx1, idx2, Ws0, Wa0, Ws1, Wa1,
                                Xhi, Xlo, Mh, Ml, W0thi, W0tlo, W1thi, W1tlo);
  gemm1<<<dim3(33, 8), 256, 0, stream>>>(Xhi, Xlo, Mh, Ml, W0thi, W0tlo,
                                         idx1, b0, Hhi, Hlo);
  gemm2<<<32, 256, 0, stream>>>(Hhi, Hlo, W1thi, W1tlo, b1, out);
}

// Round 7
// 40.636 us; speedup vs baseline: 2.2876x; 1.1858x over previous
//
#include <hip/hip_runtime.h>
#include <hip/hip_bf16.h>

// Shapes
#define B_ 64
#define L_ 64
#define D_ 512
#define F_ 32
#define H_ 512
#define M_ROWS 2048   // B*F_ neighbor rows
#define M2 2112       // + 64 [f0|m0] rows  (= 33 * 64)
#define KA 1024       // GEMM1 K ([self|aggr])

typedef __attribute__((ext_vector_type(8))) short bf16x8;
typedef __attribute__((ext_vector_type(4))) float f32x4;

__device__ __forceinline__ float leaky(float v) { return v > 0.0f ? v : 0.01f * v; }

__device__ __forceinline__ unsigned short f2bf(float v) {
  unsigned int b = __float_as_uint(v);
  unsigned int r = b + 0x7FFF + ((b >> 16) & 1);  // RNE
  return (unsigned short)(r >> 16);
}
__device__ __forceinline__ float bf2f(unsigned short h) {
  return __uint_as_float(((unsigned int)h) << 16);
}
__device__ __forceinline__ void cvt_store4(unsigned short* ph, unsigned short* pl, float4 v) {
  ushort4 h, l;
  h.x = f2bf(v.x); l.x = f2bf(v.x - bf2f(h.x));
  h.y = f2bf(v.y); l.y = f2bf(v.y - bf2f(h.y));
  h.z = f2bf(v.z); l.z = f2bf(v.z - bf2f(h.z));
  h.w = f2bf(v.w); l.w = f2bf(v.w - bf2f(h.w));
  *(ushort4*)ph = h;
  *(ushort4*)pl = l;
}

#define GLOAD16(GP, LP)                                              \
  __builtin_amdgcn_global_load_lds(                                  \
      (const __attribute__((address_space(1))) unsigned int*)(GP),   \
      (__attribute__((address_space(3))) unsigned int*)(LP), 16, 0, 0)

// ---------------- Kernel 1: fused prep (unchanged from R6) ----------------
__global__ __launch_bounds__(256) void prep(
    const float* __restrict__ x, const int* __restrict__ idx1,
    const int* __restrict__ idx2,
    const float* __restrict__ Ws0, const float* __restrict__ Wa0,
    const float* __restrict__ Ws1, const float* __restrict__ Wa1,
    unsigned short* __restrict__ Xhi, unsigned short* __restrict__ Xlo,
    unsigned short* __restrict__ Mh, unsigned short* __restrict__ Ml,
    unsigned short* __restrict__ W0thi, unsigned short* __restrict__ W0tlo,
    unsigned short* __restrict__ W1thi, unsigned short* __restrict__ W1tlo) {
  __shared__ __align__(16) char smem[33024];
  const int blk = blockIdx.x;
  const int t = threadIdx.x;

  if (blk < 64) {
    const int b = blk;
    const float* src = x + (size_t)b * (L_ * D_);
    unsigned short* dh = Xhi + (size_t)b * (L_ * D_);
    unsigned short* dl = Xlo + (size_t)b * (L_ * D_);
#pragma unroll 4
    for (int i = 0; i < 32; ++i) {
      const int f4 = t + 256 * i;
      const float4 v = *(const float4*)(src + (size_t)f4 * 4);
      cvt_store4(dh + (size_t)f4 * 4, dl + (size_t)f4 * 4, v);
    }
  } else if (blk < 320) {
    const int q = blk - 64;
    const int k0 = (q & 15) * 64;
    const int n0 = ((q >> 4) & 7) * 64;
    const int cat = q >> 7;
    float (*lt)[72] = (float(*)[72])smem;
    const float* src = (cat == 0)
        ? (k0 < 512 ? Ws0 + (size_t)k0 * H_ : Wa0 + (size_t)(k0 - 512) * H_)
        : (k0 < 512 ? Ws1 + (size_t)k0 * H_ : Wa1 + (size_t)(k0 - 512) * H_);
    unsigned short* dhi = (cat == 0) ? W0thi : W1thi;
    unsigned short* dlo = (cat == 0) ? W0tlo : W1tlo;
#pragma unroll
    for (int i = 0; i < 4; ++i) {
      const int idx4 = t + 256 * i;
      const int kl = idx4 >> 4;
      const int n4 = (idx4 & 15) * 4;
      *(float4*)&lt[kl][n4] = *(const float4*)(src + (size_t)kl * H_ + n0 + n4);
    }
    __syncthreads();
#pragma unroll
    for (int i = 0; i < 4; ++i) {
      const int idx4 = t + 256 * i;
      const int nl = idx4 >> 4;
      const int k4 = (idx4 & 15) * 4;
      ushort4 h, l;
      const float v0 = lt[k4 + 0][nl], v1 = lt[k4 + 1][nl];
      const float v2 = lt[k4 + 2][nl], v3 = lt[k4 + 3][nl];
      h.x = f2bf(v0); l.x = f2bf(v0 - bf2f(h.x));
      h.y = f2bf(v1); l.y = f2bf(v1 - bf2f(h.y));
      h.z = f2bf(v2); l.z = f2bf(v2 - bf2f(h.z));
      h.w = f2bf(v3); l.w = f2bf(v3 - bf2f(h.w));
      *(ushort4*)(dhi + (size_t)(n0 + nl) * KA + k0 + k4) = h;
      *(ushort4*)(dlo + (size_t)(n0 + nl) * KA + k0 + k4) = l;
    }
  } else {
    const int q = blk - 320;
    const int b = q >> 2;
    const int nt0 = (q & 3) * 2;
    unsigned int* cnt = (unsigned int*)smem;               // [33][64]
    unsigned short* Cm = (unsigned short*)(smem + 8448);   // [48][64]
    unsigned short* XTh = (unsigned short*)(smem + 14592); // [64][72]
    unsigned short* XTl = XTh + 64 * 72;
    const int lane = t & 63;
    const int w = t >> 6;
    const int lr = lane & 15;
    const int kb8 = (lane >> 4) * 8;

#pragma unroll
    for (int i = 0; i < 9; ++i) { const int p = t + 256 * i; if (p < 2112) cnt[p] = 0u; }
#pragma unroll
    for (int i = 0; i < 12; ++i) Cm[t + 256 * i] = 0;
    __syncthreads();
#pragma unroll
    for (int i = 0; i < 4; ++i) {
      const int j = t + 256 * i;
      atomicAdd(&cnt[(j >> 5) * 64 + idx2[(size_t)b * 1024 + j]], 1u);
    }
    if (t < 32) atomicAdd(&cnt[32 * 64 + idx1[b * F_ + t]], 1u);
    __syncthreads();
#pragma unroll
    for (int i = 0; i < 9; ++i) {
      const int p = t + 256 * i;
      if (p < 2112) Cm[p] = f2bf((float)cnt[p] * 0.03125f);
    }
    __syncthreads();
    bf16x8 Af[3][2];
#pragma unroll
    for (int mi = 0; mi < 3; ++mi)
#pragma unroll
      for (int kt = 0; kt < 2; ++kt)
        Af[mi][kt] = *(const bf16x8*)&Cm[(mi * 16 + lr) * 64 + kt * 32 + kb8];

#pragma unroll
    for (int tt = 0; tt < 2; ++tt) {
      const int nbase = (nt0 + tt) * 64;
#pragma unroll
      for (int i = 0; i < 4; ++i) {
        const int f4 = t + 256 * i;
        const int l = f4 >> 4;
        const int c4 = (f4 & 15) * 4;
        const float4 v = *(const float4*)(x + (size_t)b * (L_ * D_) + (size_t)l * D_ + nbase + c4);
        unsigned short h;
        h = f2bf(v.x); XTh[(c4 + 0) * 72 + l] = h; XTl[(c4 + 0) * 72 + l] = f2bf(v.x - bf2f(h));
        h = f2bf(v.y); XTh[(c4 + 1) * 72 + l] = h; XTl[(c4 + 1) * 72 + l] = f2bf(v.y - bf2f(h));
        h = f2bf(v.z); XTh[(c4 + 2) * 72 + l] = h; XTl[(c4 + 2) * 72 + l] = f2bf(v.z - bf2f(h));
        h = f2bf(v.w); XTh[(c4 + 3) * 72 + l] = h; XTl[(c4 + 3) * 72 + l] = f2bf(v.w - bf2f(h));
      }
      __syncthreads();
      f32x4 acc[3] = {};
#pragma unroll
      for (int kt = 0; kt < 2; ++kt) {
        const bf16x8 Bh = *(const bf16x8*)&XTh[(w * 16 + lr) * 72 + kt * 32 + kb8];
        const bf16x8 Bl = *(const bf16x8*)&XTl[(w * 16 + lr) * 72 + kt * 32 + kb8];
#pragma unroll
        for (int mi = 0; mi < 3; ++mi) {
          acc[mi] = __builtin_amdgcn_mfma_f32_16x16x32_bf16(Af[mi][kt], Bh, acc[mi], 0, 0, 0);
          acc[mi] = __builtin_amdgcn_mfma_f32_16x16x32_bf16(Af[mi][kt], Bl, acc[mi], 0, 0, 0);
        }
      }
      const int col = nbase + w * 16 + lr;
#pragma unroll
      for (int mi = 0; mi < 3; ++mi)
#pragma unroll
        for (int r = 0; r < 4; ++r) {
          const int row48 = mi * 16 + (lane >> 4) * 4 + r;
          if (row48 > 32) continue;
          const size_t Mrow = (row48 < 32) ? (size_t)(b * F_ + row48) : (size_t)(M_ROWS + b);
          const float v = acc[mi][r];
          const unsigned short h = f2bf(v);
          Mh[Mrow * 512 + col] = h;
          Ml[Mrow * 512 + col] = f2bf(v - bf2f(h));
        }
      __syncthreads();
    }
  }
}

// ---------------- Kernel 2: MFMA GEMM, BM=64 BN=32, 528 blocks, XCD swizzle -
// grid 528 (= 8 XCDs * 66). Swizzled so each XCD owns ~4 contiguous bm-tiles
// (gathered X rows become its-own-L2 hits). 4 waves: wr=M-half, wc=N-half.
// LDS 48KB (2 bufs x [Ah64|Al64|Bh32|Bl32] x 64k) -> 2 blocks/CU resident.
__global__ __launch_bounds__(256) void gemm1(
    const unsigned short* __restrict__ Xhi, const unsigned short* __restrict__ Xlo,
    const unsigned short* __restrict__ Mh, const unsigned short* __restrict__ Ml,
    const unsigned short* __restrict__ Wthi, const unsigned short* __restrict__ Wtlo,
    const int* __restrict__ idx1, const float* __restrict__ b0,
    unsigned short* __restrict__ Hhi, unsigned short* __restrict__ Hlo) {
  __shared__ unsigned short lds[24576];  // 48 KB
  const int tid = threadIdx.x;
  const int lane = tid & 63;
  const int w = tid >> 6;
  const int wr = w >> 1, wc = w & 1;
  const int lr = lane & 15;
  const int kb = lane >> 4;
  const int swz = lr & 7;
  const int rsel = lane >> 3;
  const int cbs = ((lane & 7) ^ rsel) * 8;

  // bijective XCD-chunk swizzle: 528 = 8*66; xcd gets 66 consecutive tiles
  const int o = blockIdx.x;
  const int s = (o & 7) * 66 + (o >> 3);
  const int bmi = s >> 4;   // 0..32
  const int bni = s & 15;   // 0..15
  const int bm = bmi * 64;
  const int bn = bni * 32;

  int xrow[8];
  if (w < 2) {
#pragma unroll
    for (int i = 0; i < 8; ++i) {
      const int R = bm + rsel + 8 * i;
      if (bmi < 32) xrow[i] = (R >> 5) * 64 + idx1[R];
      else          xrow[i] = (R - M_ROWS) * 64;  // f0 row of batch
    }
  }
  const unsigned short* Xp = (w == 0) ? Xhi : Xlo;
  const unsigned short* Mp = (w == 0) ? Mh : Ml;
  const unsigned short* Wp = (w == 2) ? Wthi : Wtlo;
  const unsigned short* mbase = Mp + (size_t)(bm + rsel) * 512 + cbs;
  const unsigned short* wbase = Wp + (size_t)(bn + rsel) * KA + cbs;
  // plane base (shorts): Ah@0 Al@4096 Bh@8192 Bl@10240
  const int PB = (w == 0) ? 0 : (w == 1) ? 4096 : (w == 2) ? 8192 : 10240;

#define STAGE(KT, BUF)                                                        \
  {                                                                           \
    unsigned short* ldst = &lds[(BUF)*12288 + PB];                            \
    if (w < 2) {                                                              \
      if ((KT) < 8) {                                                         \
        const int co = (KT)*64 + cbs;                                         \
        _Pragma("unroll") for (int i = 0; i < 8; ++i)                         \
            GLOAD16(Xp + (size_t)xrow[i] * 512 + co, ldst + i * 512);         \
      } else {                                                                \
        const unsigned short* mb = mbase + ((KT)-8) * 64;                     \
        _Pragma("unroll") for (int i = 0; i < 8; ++i)                         \
            GLOAD16(mb + (size_t)i * 8 * 512, ldst + i * 512);                \
      }                                                                       \
    } else {                                                                  \
      const unsigned short* wb = wbase + (KT)*64;                             \
      _Pragma("unroll") for (int i = 0; i < 4; ++i)                           \
          GLOAD16(wb + (size_t)i * 8 * KA, ldst + i * 512);                   \
    }                                                                         \
  }

  f32x4 acc[2] = {};
  STAGE(0, 0);
  __syncthreads();

#define AFRAG(PL, ROW, CB) \
  (*(const bf16x8*)&lds[buf * 12288 + (PL)*4096 + (ROW)*64 + (((CB) ^ swz) * 8)])
#define BFRAG(PL, ROW, CB) \
  (*(const bf16x8*)&lds[buf * 12288 + 8192 + (PL)*2048 + (ROW)*64 + (((CB) ^ swz) * 8)])

  for (int kt = 0; kt < 16; ++kt) {
    const int buf = kt & 1;
    if (kt < 15) STAGE(kt + 1, buf ^ 1);
#pragma unroll
    for (int ks = 0; ks < 2; ++ks) {
      const int c = ks * 4 + kb;
      const bf16x8 Ah0 = AFRAG(0, wr * 32 + lr, c);
      const bf16x8 Ah1 = AFRAG(0, wr * 32 + 16 + lr, c);
      const bf16x8 Al0 = AFRAG(1, wr * 32 + lr, c);
      const bf16x8 Al1 = AFRAG(1, wr * 32 + 16 + lr, c);
      const bf16x8 Bh = BFRAG(0, wc * 16 + lr, c);
      const bf16x8 Bl = BFRAG(1, wc * 16 + lr, c);
      acc[0] = __builtin_amdgcn_mfma_f32_16x16x32_bf16(Ah0, Bh, acc[0], 0, 0, 0);
      acc[0] = __builtin_amdgcn_mfma_f32_16x16x32_bf16(Ah0, Bl, acc[0], 0, 0, 0);
      acc[0] = __builtin_amdgcn_mfma_f32_16x16x32_bf16(Al0, Bh, acc[0], 0, 0, 0);
      acc[1] = __builtin_amdgcn_mfma_f32_16x16x32_bf16(Ah1, Bh, acc[1], 0, 0, 0);
      acc[1] = __builtin_amdgcn_mfma_f32_16x16x32_bf16(Ah1, Bl, acc[1], 0, 0, 0);
      acc[1] = __builtin_amdgcn_mfma_f32_16x16x32_bf16(Al1, Bh, acc[1], 0, 0, 0);
    }
    __syncthreads();
  }
#undef AFRAG
#undef BFRAG
#undef STAGE

  // Epilogue. C/D layout: col = lane&15, row = (lane>>4)*4 + reg.
  const int col = bn + wc * 16 + lr;
  const float bias = b0[col];
  if (bmi < 32) {
    const int b = bmi * 2 + wr;  // wave wr's 32 rows = all f of this b
    float sum = 0.f;
#pragma unroll
    for (int mi = 0; mi < 2; ++mi)
#pragma unroll
      for (int r = 0; r < 4; ++r) sum += leaky(acc[mi][r] + bias);
    sum += __shfl_xor(sum, 16);
    sum += __shfl_xor(sum, 32);
    sum *= (1.0f / 32.0f);
    if (lane < 16) {
      const unsigned short h = f2bf(sum);
      Hhi[(size_t)b * KA + 512 + col] = h;
      Hlo[(size_t)b * KA + 512 + col] = f2bf(sum - bf2f(h));
    }
  } else {
#pragma unroll
    for (int mi = 0; mi < 2; ++mi)
#pragma unroll
      for (int r = 0; r < 4; ++r) {
        const int b = wr * 32 + mi * 16 + kb * 4 + r;
        const float v = leaky(acc[mi][r] + bias);
        const unsigned short h = f2bf(v);
        Hhi[(size_t)b * KA + col] = h;
        Hlo[(size_t)b * KA + col] = f2bf(v - bf2f(h));
      }
  }
}

// ---------------- Kernel 3: gemm2 split-K partials -------------------------
// grid (32 n-tiles x 8 k-chunks) = 256 blocks; each wave owns 32 k.
__global__ __launch_bounds__(256) void gemm2(
    const unsigned short* __restrict__ Hhi, const unsigned short* __restrict__ Hlo,
    const unsigned short* __restrict__ Wthi, const unsigned short* __restrict__ Wtlo,
    float* __restrict__ part) {
  __shared__ float sacc[256][17];
  const int tid = threadIdx.x;
  const int w = tid >> 6;
  const int lane = tid & 63;
  const int lr = lane & 15;
  const int kb = lane >> 4;
  const int n0 = blockIdx.x * 16;
  const int kc = blockIdx.y * 128;

  f32x4 acc[4] = {};
  const int k = kc + w * 32 + kb * 8;
  const bf16x8 Bh = *(const bf16x8*)(Wthi + (size_t)(n0 + lr) * KA + k);
  const bf16x8 Bl = *(const bf16x8*)(Wtlo + (size_t)(n0 + lr) * KA + k);
#pragma unroll
  for (int mi = 0; mi < 4; ++mi) {
    const bf16x8 Ah = *(const bf16x8*)(Hhi + (size_t)(mi * 16 + lr) * KA + k);
    const bf16x8 Al = *(const bf16x8*)(Hlo + (size_t)(mi * 16 + lr) * KA + k);
    acc[mi] = __builtin_amdgcn_mfma_f32_16x16x32_bf16(Ah, Bh, acc[mi], 0, 0, 0);
    acc[mi] = __builtin_amdgcn_mfma_f32_16x16x32_bf16(Ah, Bl, acc[mi], 0, 0, 0);
    acc[mi] = __builtin_amdgcn_mfma_f32_16x16x32_bf16(Al, Bh, acc[mi], 0, 0, 0);
  }
#pragma unroll
  for (int mi = 0; mi < 4; ++mi)
#pragma unroll
    for (int r = 0; r < 4; ++r)
      sacc[((w * 4 + mi) * 4 + kb) * 4 + r][lr] = acc[mi][r];
  __syncthreads();

  const int lr2 = tid & 15;
  const int rg = tid >> 4;
  float* pp = part + (size_t)blockIdx.y * (B_ * H_);
#pragma unroll
  for (int q = 0; q < 4; ++q) {
    const int row = rg * 4 + q;
    const int mi = row >> 4, kb2 = (row >> 2) & 3, r = row & 3;
    float s = 0.f;
#pragma unroll
    for (int w2 = 0; w2 < 4; ++w2)
      s += sacc[((w2 * 4 + mi) * 4 + kb2) * 4 + r][lr2];
    pp[(size_t)row * H_ + n0 + lr2] = s;
  }
}

// ---------------- Kernel 4: out = sum_k part + b1 ---------------------------
__global__ __launch_bounds__(256) void reduce_out(
    const float* __restrict__ part, const float* __restrict__ b1,
    float* __restrict__ out) {
  const int idx = blockIdx.x * 256 + threadIdx.x;  // float4 id, 8192 total
  const int c4 = (idx & 127) * 4;
  const size_t off = (size_t)(idx >> 7) * H_ + c4;
  float4 s = *(const float4*)(b1 + c4);
#pragma unroll
  for (int ky = 0; ky < 8; ++ky) {
    const float4 p = *(const float4*)(part + (size_t)ky * (B_ * H_) + off);
    s.x += p.x; s.y += p.y; s.z += p.z; s.w += p.w;
  }
  *(float4*)(out + off) = s;
}

extern "C" void kernel_launch(void* const* d_in, const int* in_sizes, int n_in,
                              void* d_out, int out_size, void* d_ws, size_t ws_size,
                              hipStream_t stream) {
  const float* x    = (const float*)d_in[0];
  const int*   idx1 = (const int*)d_in[1];
  const int*   idx2 = (const int*)d_in[2];
  const float* Wa0  = (const float*)d_in[3];
  const float* b0   = (const float*)d_in[4];
  const float* Ws0  = (const float*)d_in[5];
  const float* Wa1  = (const float*)d_in[6];
  const float* b1   = (const float*)d_in[7];
  const float* Ws1  = (const float*)d_in[8];
  float* out = (float*)d_out;

  unsigned short* wsu = (unsigned short*)d_ws;
  unsigned short* Xhi   = wsu;                          // 4096*512
  unsigned short* Xlo   = Xhi + (size_t)4096 * 512;
  unsigned short* Mh    = Xlo + (size_t)4096 * 512;     // 2112*512
  unsigned short* Ml    = Mh + (size_t)M2 * 512;
  unsigned short* W0thi = Ml + (size_t)M2 * 512;        // 512*1024 each
  unsigned short* W0tlo = W0thi + (size_t)H_ * KA;
  unsigned short* W1thi = W0tlo + (size_t)H_ * KA;
  unsigned short* W1tlo = W1thi + (size_t)H_ * KA;
  unsigned short* Hhi   = W1tlo + (size_t)H_ * KA;      // 64*1024 each
  unsigned short* Hlo   = Hhi + (size_t)B_ * KA;
  float* part = (float*)(Hlo + (size_t)B_ * KA);        // 8*64*512 fp32

  prep<<<576, 256, 0, stream>>>(x, idx1, idx2, Ws0, Wa0, Ws1, Wa1,
                                Xhi, Xlo, Mh, Ml, W0thi, W0tlo, W1thi, W1tlo);
  gemm1<<<528, 256, 0, stream>>>(Xhi, Xlo, Mh, Ml, W0thi, W0tlo,
                                 idx1, b0, Hhi, Hlo);
  gemm2<<<dim3(32, 8), 256, 0, stream>>>(Hhi, Hlo, W1thi, W1tlo, part);
  reduce_out<<<32, 256, 0, stream>>>(part, b1, out);
}